// Round 2
// baseline (446.647 us; speedup 1.0000x reference)
//
#include <hip/hip_runtime.h>

typedef __attribute__((ext_vector_type(4))) float f32x4;
typedef __attribute__((ext_vector_type(8))) short short8;

#define B_ 4
#define N_ 8192
#define E_ 131072
#define R_ 16
#define H_ 128
#define OUT_ 32
#define NKEYS (B_*N_*R_)   /* 524288 */
#define NEDGE (B_*E_)      /* 524288 */
#define TILE 64
#define NTILE (N_/TILE)    /* 128 */
#define CAP 128            /* max edges per (tile, rel); lambda=64, 8 sigma */
#define RMAX 8             /* CAP/16 */

__device__ __forceinline__ unsigned short f2bf(float f){
  unsigned int u = __float_as_uint(f);
  u = (u + 0x7fffu + ((u>>16)&1u)) >> 16;
  return (unsigned short)u;
}
__device__ __forceinline__ float bf2f(unsigned short s){
  return __uint_as_float(((unsigned int)s)<<16);
}

__device__ __forceinline__ void glds16(const void* g, void* l){
  __builtin_amdgcn_global_load_lds((const __attribute__((address_space(1))) unsigned int*)g,
                                   (__attribute__((address_space(3))) unsigned int*)l,
                                   16, 0, 0);
}

// ---------------- CSR build: key = ((b*16 + r)*8192 + dst) ----------------

__global__ void hist_k(const int* __restrict__ et, const int* __restrict__ ec,
                       int* __restrict__ cnt){
  int e = blockIdx.x*256 + threadIdx.x;
  int b = e >> 17;                  // E = 2^17
  int dst = et[2*e+1];
  int r  = ec[e];
  atomicAdd(&cnt[(((b<<4)+r)<<13) + dst], 1);
}

__global__ void scan1_k(const int* __restrict__ in, int* __restrict__ out,
                        int* __restrict__ bsum){
  __shared__ int lds[256];
  int t = threadIdx.x;
  int base = blockIdx.x*1024 + t*4;
  int4 v = *(const int4*)(in + base);
  lds[t] = v.x+v.y+v.z+v.w;
  __syncthreads();
  for (int off=1; off<256; off<<=1){
    int x = (t>=off) ? lds[t-off] : 0;
    __syncthreads();
    lds[t] += x;
    __syncthreads();
  }
  if (t==255) bsum[blockIdx.x] = lds[255];
  int pre = (t==0) ? 0 : lds[t-1];
  int4 o;
  o.x = pre; o.y = o.x+v.x; o.z = o.y+v.y; o.w = o.z+v.z;
  *(int4*)(out + base) = o;
}

__global__ void scan2_k(int* __restrict__ bsum){
  __shared__ int lds[256];
  int t = threadIdx.x;
  int2 v = *(const int2*)(bsum + t*2);
  lds[t] = v.x+v.y;
  __syncthreads();
  for (int off=1; off<256; off<<=1){
    int x = (t>=off) ? lds[t-off] : 0;
    __syncthreads();
    lds[t] += x;
    __syncthreads();
  }
  int pre = (t==0) ? 0 : lds[t-1];
  int2 o; o.x = pre; o.y = pre + v.x;
  *(int2*)(bsum + t*2) = o;
}

__global__ void scan3_k(int* __restrict__ out, const int* __restrict__ bsum){
  int t = threadIdx.x;
  int base = blockIdx.x*1024 + t*4;
  int add = bsum[blockIdx.x];
  int4 v = *(int4*)(out + base);
  v.x+=add; v.y+=add; v.z+=add; v.w+=add;
  *(int4*)(out + base) = v;
  if (blockIdx.x==0 && t==0) out[NKEYS] = NEDGE;
}

__global__ void fill_k(const int* __restrict__ et, const int* __restrict__ ec,
                       const float* __restrict__ me, const int* __restrict__ off,
                       int* __restrict__ cur, uint2* __restrict__ erec){
  int e = blockIdx.x*256 + threadIdx.x;
  int b = e >> 17;
  int src = et[2*e];
  int dst = et[2*e+1];
  int r  = ec[e];
  int key = (((b<<4)+r)<<13) + dst;
  int pos = off[key] + atomicAdd(&cur[key], 1);
  erec[pos] = make_uint2((unsigned)src, __float_as_uint(me[e]));
}

// ---------------- feature prep ----------------

__global__ void embed_k(const int* __restrict__ cls, const float* __restrict__ emb,
                        unsigned short* __restrict__ h){
  int t = blockIdx.x*256 + threadIdx.x;   // B*N*32 threads, 4 feats each
  int node = t>>5, c = t&31;
  int cl = cls[node];
  float4 v = *(const float4*)(emb + cl*H_ + c*4);
  uint2 o;
  o.x = f2bf(v.x) | ((unsigned int)f2bf(v.y)<<16);
  o.y = f2bf(v.z) | ((unsigned int)f2bf(v.w)<<16);
  *(uint2*)(h + node*H_ + c*4) = o;
}

// Wt[r][n][k] = bf16(W[r][k][n]); all three W's in one kernel
__global__ void wtrans_all(const float* __restrict__ W1, const float* __restrict__ W2,
                           const float* __restrict__ W3,
                           unsigned short* __restrict__ W1t,
                           unsigned short* __restrict__ W2t,
                           unsigned short* __restrict__ W3t){
  int t = blockIdx.x*256 + threadIdx.x;
  if (t < R_*H_*H_) {
    int k = t & 127, n = (t>>7) & 127, r = t >> 14;
    W1t[t] = f2bf(W1[(r*H_ + k)*H_ + n]);
  } else if (t < 2*R_*H_*H_) {
    int u = t - R_*H_*H_;
    int k = u & 127, n = (u>>7) & 127, r = u >> 14;
    W2t[u] = f2bf(W2[(r*H_ + k)*H_ + n]);
  } else {
    int u = t - 2*R_*H_*H_;
    if (u < R_*OUT_*H_) {
      int k = u & 127, n = (u>>7) & 31, r = u >> 12;
      W3t[u] = f2bf(W3[(r*H_ + k)*OUT_ + n]);
    }
  }
}

// ---------------- fused aggregate + GEMM layer ----------------
// Block = 64 dst rows of one batch; 256 threads = 4 waves; wave w owns
// MFMA k-chunk [w*32, w*32+32). Per relation: edge rows staged to LDS via
// global_load_lds (chunk-XOR pre-swizzled global source), per-lane fp32
// edge-sum -> bf16 A-frag in regs -> MFMA vs Wt[r]. Partial accs combined
// across waves via swizzled LDS atomicAdd at the end.

template<int NOUT>
__global__ __launch_bounds__(256, 2) void layer_k(
    const unsigned short* __restrict__ h_in,   // bf16 [B*N*H]
    const unsigned short* __restrict__ Wt,     // bf16 [R][NOUT][H]
    const int* __restrict__ csr_off,
    const uint2* __restrict__ erec,            // {src, mask bits}
    unsigned short* __restrict__ h_out,        // bf16 relu'd (NOUT=128)
    float* __restrict__ logits)                // fp32 (NOUT=32)
{
  constexpr int NI = NOUT/16;
  __shared__ __align__(16) unsigned short Hedge[2][CAP*H_];  // 64KB
  __shared__ float masks_s[2][CAP];
  __shared__ int rowoff_s[R_*(TILE+1)];

  const int tid  = threadIdx.x;
  const int lane = tid & 63;
  const int w    = tid >> 6;            // wave id = k-chunk
  const int b    = blockIdx.x >> 7;     // NTILE = 128
  const int tile = blockIdx.x & 127;
  const int dst0 = tile * TILE;
  const int c16  = lane & 15;
  const int g    = lane >> 4;

  // prologue: all (rel,row) csr offsets -> LDS
  for (int i = tid; i < R_*(TILE+1); i += 256) {
    int r = i / (TILE+1);
    int row = i - r*(TILE+1);
    rowoff_s[i] = csr_off[(((b<<4)+r)<<13) + dst0 + row];
  }
  __syncthreads();

  f32x4 acc[4][NI];
  #pragma unroll
  for (int i=0;i<4;i++)
    #pragma unroll
    for (int j=0;j<NI;j++)
      acc[i][j] = f32x4{0.f,0.f,0.f,0.f};

  uint2 recA[RMAX], recB[RMAX];

#define RELRANGE(rr, e0v, cntv) \
  int e0v = rowoff_s[(rr)*(TILE+1)]; \
  int cntv = rowoff_s[(rr)*(TILE+1) + TILE] - e0v; \
  if (cntv > CAP) cntv = CAP;

#define LOAD_REC(rr, dreg) do { \
  RELRANGE(rr, e0_, cnt_) \
  _Pragma("unroll") \
  for (int i_ = 0; i_ < RMAX; ++i_) { \
    int e_ = i_*16 + (tid>>4); \
    if (e_ < cnt_) dreg[i_] = erec[e0_ + e_]; \
  } } while(0)

#define ISSUE_GLLD(rr, sreg) do { \
  RELRANGE(rr, e0_, cnt_) \
  (void)e0_; \
  int par_ = (rr) & 1; \
  _Pragma("unroll") \
  for (int i_ = 0; i_ < RMAX; ++i_) { \
    int e_ = i_*16 + (tid>>4); \
    if (e_ < cnt_) { \
      unsigned src_ = sreg[i_].x; \
      const unsigned short* gp_ = h_in + ((((unsigned)b<<13) + src_)<<7) \
                                       + (((unsigned)c16 ^ (unsigned)(e_&7))<<3); \
      unsigned short* lp_ = &Hedge[par_][(i_*16 + w*4)*H_]; \
      glds16(gp_, lp_); \
      if ((lane & 15) == 0) masks_s[par_][e_] = __uint_as_float(sreg[i_].y); \
    } \
  } } while(0)

#define PHASE_COMPUTE(rr) do { \
  RELRANGE(rr, e0_, cnt_) \
  int par_ = (rr) & 1; \
  const int kbyte_ = w*64 + g*16; \
  short8 bfrag[NI]; \
  _Pragma("unroll") \
  for (int ni_ = 0; ni_ < NI; ++ni_) { \
    int n_ = ni_*16 + c16; \
    bfrag[ni_] = *(const short8*)(Wt + ((rr)*NOUT + n_)*H_ + w*32 + (g<<3)); \
  } \
  _Pragma("unroll") \
  for (int mi_ = 0; mi_ < 4; ++mi_) { \
    int row_ = mi_*16 + c16; \
    int rs_ = rowoff_s[(rr)*(TILE+1) + row_] - e0_; \
    int re_ = rowoff_s[(rr)*(TILE+1) + row_ + 1] - e0_; \
    if (re_ > cnt_) re_ = cnt_; \
    float aa_[8]; \
    _Pragma("unroll") \
    for (int u_=0; u_<8; ++u_) aa_[u_] = 0.f; \
    for (int e_ = rs_; e_ < re_; ++e_) { \
      float mk_ = masks_s[par_][e_]; \
      unsigned off_ = (unsigned)e_*256u + (unsigned)(kbyte_ ^ ((e_&7)<<4)); \
      short8 hv_ = *(const short8*)((const char*)Hedge[par_] + off_); \
      _Pragma("unroll") \
      for (int u_=0; u_<8; ++u_) aa_[u_] += mk_ * bf2f((unsigned short)hv_[u_]); \
    } \
    short8 af_; \
    _Pragma("unroll") \
    for (int u_=0; u_<8; ++u_) af_[u_] = (short)f2bf(aa_[u_]); \
    _Pragma("unroll") \
    for (int ni_ = 0; ni_ < NI; ++ni_) \
      acc[mi_][ni_] = __builtin_amdgcn_mfma_f32_16x16x32_bf16(af_, bfrag[ni_], acc[mi_][ni_], 0,0,0); \
  } } while(0)

  // pipeline prologue
  LOAD_REC(0, recA);
  ISSUE_GLLD(0, recA);
  LOAD_REC(1, recB);
  __syncthreads();

  for (int r = 0; r < R_; r += 2) {
    if (r+1 < R_) ISSUE_GLLD(r+1, recB);
    if (r+2 < R_) LOAD_REC(r+2, recA);
    PHASE_COMPUTE(r);
    __syncthreads();
    if (r+2 < R_) ISSUE_GLLD(r+2, recA);
    if (r+3 < R_) LOAD_REC(r+3, recB);
    PHASE_COMPUTE(r+1);
    __syncthreads();
  }

  // ---- cross-wave combine (4 k-chunk partials) via swizzled LDS atomics ----
  float* comb = (float*)&Hedge[0][0];           // [TILE][NOUT] fp32, swizzled
  for (int i = tid; i < TILE*NOUT/4; i += 256)
    ((f32x4*)comb)[i] = f32x4{0.f,0.f,0.f,0.f};
  __syncthreads();

  #pragma unroll
  for (int mi = 0; mi < 4; ++mi)
    #pragma unroll
    for (int ni = 0; ni < NI; ++ni)
      #pragma unroll
      for (int j = 0; j < 4; ++j) {
        int m = mi*16 + (g<<2) + j;
        int n = ni*16 + c16;
        unsigned byt = (unsigned)(m*NOUT*4) + ((unsigned)(n*4) ^ (unsigned)((m&7)<<4));
        atomicAdd((float*)((char*)comb + byt), acc[mi][ni][j]);
      }
  __syncthreads();

  if constexpr (NOUT == 128) {
    const int row = tid >> 2;
    const int c0 = (tid & 3) * 32;
    const int node = (b<<13) + dst0 + row;
    #pragma unroll
    for (int i2 = 0; i2 < 4; ++i2) {
      float vv[8];
      #pragma unroll
      for (int u2 = 0; u2 < 2; ++u2) {
        int c = c0 + i2*8 + u2*4;
        unsigned byt = (unsigned)(row*512) + ((unsigned)(c*4) ^ (unsigned)((row&7)<<4));
        f32x4 x = *(const f32x4*)((const char*)comb + byt);
        vv[u2*4+0]=x[0]; vv[u2*4+1]=x[1]; vv[u2*4+2]=x[2]; vv[u2*4+3]=x[3];
      }
      uint4 pk;
      pk.x = f2bf(fmaxf(vv[0],0.f)) | ((unsigned)f2bf(fmaxf(vv[1],0.f))<<16);
      pk.y = f2bf(fmaxf(vv[2],0.f)) | ((unsigned)f2bf(fmaxf(vv[3],0.f))<<16);
      pk.z = f2bf(fmaxf(vv[4],0.f)) | ((unsigned)f2bf(fmaxf(vv[5],0.f))<<16);
      pk.w = f2bf(fmaxf(vv[6],0.f)) | ((unsigned)f2bf(fmaxf(vv[7],0.f))<<16);
      *(uint4*)(h_out + (size_t)node*128 + c0 + i2*8) = pk;
    }
  } else {
    const int row = tid >> 2;
    const int c0 = (tid & 3) * 8;
    const int node = (b<<13) + dst0 + row;
    #pragma unroll
    for (int u2 = 0; u2 < 2; ++u2) {
      int c = c0 + u2*4;
      unsigned byt = (unsigned)(row*128) + ((unsigned)(c*4) ^ (unsigned)((row&7)<<4));
      f32x4 x = *(const f32x4*)((const char*)comb + byt);
      *(f32x4*)(logits + (size_t)node*32 + c) = x;
    }
  }
#undef RELRANGE
#undef LOAD_REC
#undef ISSUE_GLLD
#undef PHASE_COMPUTE
}

__global__ void softmax_k(const float* __restrict__ logits,
                          const float* __restrict__ mobj,
                          float* __restrict__ out){
  int row = blockIdx.x*256 + threadIdx.x;  // 32768 rows
  float v[32];
  const float4* p = (const float4*)(logits + row*32);
  #pragma unroll
  for (int i=0;i<8;i++){
    float4 x = p[i];
    v[4*i]=x.x; v[4*i+1]=x.y; v[4*i+2]=x.z; v[4*i+3]=x.w;
  }
  float mx = v[0];
  #pragma unroll
  for (int i=1;i<32;i++) mx = fmaxf(mx, v[i]);
  float s = 0.f;
  #pragma unroll
  for (int i=0;i<32;i++){ v[i] = __expf(v[i]-mx); s += v[i]; }
  float sc = mobj[row] / s;
  float4* qo = (float4*)(out + row*32);
  #pragma unroll
  for (int i=0;i<8;i++){
    float4 x;
    x.x=v[4*i]*sc; x.y=v[4*i+1]*sc; x.z=v[4*i+2]*sc; x.w=v[4*i+3]*sc;
    qo[i] = x;
  }
}

extern "C" void kernel_launch(void* const* d_in, const int* in_sizes, int n_in,
                              void* d_out, int out_size, void* d_ws, size_t ws_size,
                              hipStream_t stream){
  const int*   cls   = (const int*)  d_in[0];
  // d_in[1] states_objects: unused by reference
  const int*   et    = (const int*)  d_in[2];
  const int*   ec    = (const int*)  d_in[3];
  const float* mobj  = (const float*)d_in[4];
  const float* medge = (const float*)d_in[5];
  const float* emb   = (const float*)d_in[6];
  const float* W1    = (const float*)d_in[7];
  const float* W2    = (const float*)d_in[8];
  const float* W3    = (const float*)d_in[9];
  float* out = (float*)d_out;

  char* ws = (char*)d_ws;
  size_t o = 0;
  auto alloc = [&](size_t bytes)->char*{
    char* p = ws + o;
    o += (bytes + 255) & ~(size_t)255;
    return p;
  };
  unsigned short* hA    = (unsigned short*)alloc((size_t)B_*N_*H_*2);
  unsigned short* hB    = (unsigned short*)alloc((size_t)B_*N_*H_*2);
  float*          lg    = (float*)alloc((size_t)B_*N_*OUT_*4);
  unsigned short* W1t   = (unsigned short*)alloc((size_t)R_*H_*H_*2);
  unsigned short* W2t   = (unsigned short*)alloc((size_t)R_*H_*H_*2);
  unsigned short* W3t   = (unsigned short*)alloc((size_t)R_*OUT_*H_*2);
  int*            cnt   = (int*)alloc((size_t)NKEYS*4);
  int*            off   = (int*)alloc((size_t)(NKEYS+1)*4);
  int*            bsum  = (int*)alloc(512*4);
  uint2*          erec  = (uint2*)alloc((size_t)NEDGE*8);
  (void)ws_size; (void)in_sizes; (void)n_in; (void)out_size;

  // CSR build: histogram -> exclusive scan -> fill (key = (b, rel, dst))
  hipMemsetAsync(cnt, 0, (size_t)NKEYS*4, stream);
  hipLaunchKernelGGL(hist_k,  dim3(NEDGE/256), dim3(256), 0, stream, et, ec, cnt);
  hipLaunchKernelGGL(scan1_k, dim3(512), dim3(256), 0, stream, cnt, off, bsum);
  hipLaunchKernelGGL(scan2_k, dim3(1),   dim3(256), 0, stream, bsum);
  hipLaunchKernelGGL(scan3_k, dim3(512), dim3(256), 0, stream, off, bsum);
  hipMemsetAsync(cnt, 0, (size_t)NKEYS*4, stream);   // cnt -> cursor
  hipLaunchKernelGGL(fill_k,  dim3(NEDGE/256), dim3(256), 0, stream, et, ec, medge, off, cnt, erec);

  // h0 = bf16(embed[class]);  W -> bf16 [r][n][k]
  hipLaunchKernelGGL(embed_k, dim3(B_*N_*32/256), dim3(256), 0, stream, cls, emb, hA);
  hipLaunchKernelGGL(wtrans_all, dim3((2*R_*H_*H_ + R_*OUT_*H_)/256), dim3(256), 0, stream,
                     W1, W2, W3, W1t, W2t, W3t);

  // 3 fused aggregate+GEMM layers, then softmax*mask
  hipLaunchKernelGGL((layer_k<128>), dim3(B_*NTILE), dim3(256), 0, stream,
                     hA, W1t, off, erec, hB, (float*)nullptr);
  hipLaunchKernelGGL((layer_k<128>), dim3(B_*NTILE), dim3(256), 0, stream,
                     hB, W2t, off, erec, hA, (float*)nullptr);
  hipLaunchKernelGGL((layer_k<32>),  dim3(B_*NTILE), dim3(256), 0, stream,
                     hA, W3t, off, erec, (unsigned short*)nullptr, lg);
  hipLaunchKernelGGL(softmax_k, dim3(B_*N_/256), dim3(256), 0, stream, lg, mobj, out);
}

// Round 3
// 390.899 us; speedup vs baseline: 1.1426x; 1.1426x over previous
//
#include <hip/hip_runtime.h>

typedef __attribute__((ext_vector_type(4))) float f32x4;
typedef __attribute__((ext_vector_type(8))) short short8;

#define B_ 4
#define N_ 8192
#define E_ 131072
#define R_ 16
#define H_ 128
#define OUT_ 32
#define NKEYS (B_*N_*R_)   /* 524288 */
#define NEDGE (B_*E_)      /* 524288 */
#define TILE 64
#define NTILE (N_/TILE)    /* 128 */

__device__ __forceinline__ unsigned short f2bf(float f){
  unsigned int u = __float_as_uint(f);
  u = (u + 0x7fffu + ((u>>16)&1u)) >> 16;
  return (unsigned short)u;
}
__device__ __forceinline__ float bfh(unsigned u, int hi){
  return __uint_as_float(hi ? (u & 0xffff0000u) : (u << 16));
}

// ---------------- CSR build: key = ((b*16 + r)*8192 + dst) ----------------

__global__ void hist_k(const int* __restrict__ et, const int* __restrict__ ec,
                       int* __restrict__ cnt){
  int e = blockIdx.x*256 + threadIdx.x;
  int b = e >> 17;                  // E = 2^17
  int dst = et[2*e+1];
  int r  = ec[e];
  atomicAdd(&cnt[(((b<<4)+r)<<13) + dst], 1);
}

__global__ void scan1_k(const int* __restrict__ in, int* __restrict__ out,
                        int* __restrict__ bsum){
  __shared__ int lds[256];
  int t = threadIdx.x;
  int base = blockIdx.x*1024 + t*4;
  int4 v = *(const int4*)(in + base);
  lds[t] = v.x+v.y+v.z+v.w;
  __syncthreads();
  for (int off=1; off<256; off<<=1){
    int x = (t>=off) ? lds[t-off] : 0;
    __syncthreads();
    lds[t] += x;
    __syncthreads();
  }
  if (t==255) bsum[blockIdx.x] = lds[255];
  int pre = (t==0) ? 0 : lds[t-1];
  int4 o;
  o.x = pre; o.y = o.x+v.x; o.z = o.y+v.y; o.w = o.z+v.z;
  *(int4*)(out + base) = o;
}

__global__ void scan2_k(int* __restrict__ bsum){
  __shared__ int lds[256];
  int t = threadIdx.x;
  int2 v = *(const int2*)(bsum + t*2);
  lds[t] = v.x+v.y;
  __syncthreads();
  for (int off=1; off<256; off<<=1){
    int x = (t>=off) ? lds[t-off] : 0;
    __syncthreads();
    lds[t] += x;
    __syncthreads();
  }
  int pre = (t==0) ? 0 : lds[t-1];
  int2 o; o.x = pre; o.y = pre + v.x;
  *(int2*)(bsum + t*2) = o;
}

__global__ void scan3_k(int* __restrict__ out, const int* __restrict__ bsum){
  int t = threadIdx.x;
  int base = blockIdx.x*1024 + t*4;
  int add = bsum[blockIdx.x];
  int4 v = *(int4*)(out + base);
  v.x+=add; v.y+=add; v.z+=add; v.w+=add;
  *(int4*)(out + base) = v;
  if (blockIdx.x==0 && t==0) out[NKEYS] = NEDGE;
}

__global__ void fill_k(const int* __restrict__ et, const int* __restrict__ ec,
                       const float* __restrict__ me, const int* __restrict__ off,
                       int* __restrict__ cur, uint2* __restrict__ erec){
  int e = blockIdx.x*256 + threadIdx.x;
  int b = e >> 17;
  int src = et[2*e];
  int dst = et[2*e+1];
  int r  = ec[e];
  int key = (((b<<4)+r)<<13) + dst;
  int pos = off[key] + atomicAdd(&cur[key], 1);
  erec[pos] = make_uint2((unsigned)src, __float_as_uint(me[e]));
}

// ---------------- feature prep ----------------

__global__ void embed_k(const int* __restrict__ cls, const float* __restrict__ emb,
                        unsigned short* __restrict__ h){
  int t = blockIdx.x*256 + threadIdx.x;   // B*N*32 threads, 4 feats each
  int node = t>>5, c = t&31;
  int cl = cls[node];
  float4 v = *(const float4*)(emb + cl*H_ + c*4);
  uint2 o;
  o.x = f2bf(v.x) | ((unsigned int)f2bf(v.y)<<16);
  o.y = f2bf(v.z) | ((unsigned int)f2bf(v.w)<<16);
  *(uint2*)(h + node*H_ + c*4) = o;
}

// Wt[r][n][k] = bf16(W[r][k][n]); all three W's in one kernel
__global__ void wtrans_all(const float* __restrict__ W1, const float* __restrict__ W2,
                           const float* __restrict__ W3,
                           unsigned short* __restrict__ W1t,
                           unsigned short* __restrict__ W2t,
                           unsigned short* __restrict__ W3t){
  int t = blockIdx.x*256 + threadIdx.x;
  if (t < R_*H_*H_) {
    int k = t & 127, n = (t>>7) & 127, r = t >> 14;
    W1t[t] = f2bf(W1[(r*H_ + k)*H_ + n]);
  } else if (t < 2*R_*H_*H_) {
    int u = t - R_*H_*H_;
    int k = u & 127, n = (u>>7) & 127, r = u >> 14;
    W2t[u] = f2bf(W2[(r*H_ + k)*H_ + n]);
  } else {
    int u = t - 2*R_*H_*H_;
    if (u < R_*OUT_*H_) {
      int k = u & 127, n = (u>>7) & 31, r = u >> 12;
      W3t[u] = f2bf(W3[(r*H_ + k)*OUT_ + n]);
    }
  }
}

// ---------------- fused aggregate + GEMM layer ----------------
// Block = 64 dst rows, 512 threads (8 waves). Aggregation: thread (row, q)
// owns a 16-feat slice of one row; edge recs prefetched one rel ahead into
// regs; h gathers issued at phase start, consumed AFTER the MFMA step (one
// exposed latency per rel). A-tile bf16 in XOR-swizzled LDS, double-buffered
// -> 1 barrier/rel. MFMA: NOUT=128: wave=ni tile, full K. NOUT=32: wave=
// (ni, ks) k-split, LDS-atomic combine at end.

template<int NOUT>
__global__ __launch_bounds__(512, 4) void layer_k(
    const unsigned short* __restrict__ h_in,   // bf16 [B*N*H]
    const unsigned short* __restrict__ Wt,     // bf16 [R][NOUT][H]
    const int* __restrict__ csr_off,
    const uint2* __restrict__ erec,            // {src, mask bits}
    unsigned short* __restrict__ h_out,        // bf16 relu'd (NOUT=128)
    float* __restrict__ logits)                // fp32 (NOUT=32)
{
  __shared__ __align__(16) unsigned short A_s[2][TILE*H_];  // 2 x 16KB
  __shared__ int rowoff_s[R_*(TILE+1)];                     // 4160 B

  const int tid  = threadIdx.x;
  const int lane = tid & 63;
  const int w    = tid >> 6;
  const int c16  = lane & 15;
  const int g    = lane >> 4;
  const int b    = blockIdx.x >> 7;
  const int dst0 = (blockIdx.x & 127) * TILE;
  const int row  = tid >> 3;            // 8 threads per row
  const int q    = tid & 7;             // 16-feat slice
  const unsigned sw = (unsigned)((row & 7) << 4);
  const unsigned short* hb = h_in + ((size_t)b << 20);   // b*N*H

  for (int i = tid; i < R_*(TILE+1); i += 512) {
    int r = i / (TILE+1), rr0 = i - r*(TILE+1);
    rowoff_s[i] = csr_off[(((b<<4)+r)<<13) + dst0 + rr0];
  }
  __syncthreads();

  f32x4 acc[4];
  #pragma unroll
  for (int mi=0; mi<4; ++mi) acc[mi] = f32x4{0.f,0.f,0.f,0.f};

  uint2 recA[4], recB[4];
  uint4 hgA[4][2], hgB[4][2];
  int rsA=0, cntA=0, rsB=0, cntB=0;

#define LOAD_REC(rr, rec, rsv, cntv) do { \
  rsv = rowoff_s[(rr)*(TILE+1) + row]; \
  int re_ = rowoff_s[(rr)*(TILE+1) + row + 1]; \
  cntv = re_ - rsv; \
  _Pragma("unroll") \
  for (int i_=0;i_<4;++i_) if (i_ < cntv) rec[i_] = erec[rsv + i_]; \
} while(0)

#define GATHER(rec, cntv, hg) do { \
  _Pragma("unroll") \
  for (int i_=0;i_<4;++i_) if (i_ < cntv) { \
    const uint4* hp_ = (const uint4*)(hb + (((unsigned)rec[i_].x)<<7) + q*16); \
    hg[i_][0] = hp_[0]; hg[i_][1] = hp_[1]; \
  } \
} while(0)

#define ACC8(sarr, base, U4, m_) do { \
  sarr[base+0]+=m_*bfh(U4.x,0); sarr[base+1]+=m_*bfh(U4.x,1); \
  sarr[base+2]+=m_*bfh(U4.y,0); sarr[base+3]+=m_*bfh(U4.y,1); \
  sarr[base+4]+=m_*bfh(U4.z,0); sarr[base+5]+=m_*bfh(U4.z,1); \
  sarr[base+6]+=m_*bfh(U4.w,0); sarr[base+7]+=m_*bfh(U4.w,1); \
} while(0)

#define SUMWRITE(rr, rec, rsv, cntv, hg) do { \
  float s_[16]; \
  _Pragma("unroll") \
  for (int u_=0;u_<16;++u_) s_[u_] = 0.f; \
  _Pragma("unroll") \
  for (int i_=0;i_<4;++i_) if (i_ < cntv) { \
    float m_ = __uint_as_float(rec[i_].y); \
    ACC8(s_, 0, hg[i_][0], m_); \
    ACC8(s_, 8, hg[i_][1], m_); \
  } \
  for (int e_=4; e_<cntv; ++e_) { \
    uint2 rc_ = erec[rsv + e_]; \
    const uint4* hp_ = (const uint4*)(hb + (((unsigned)rc_.x)<<7) + q*16); \
    uint4 h0_ = hp_[0], h1_ = hp_[1]; \
    float m_ = __uint_as_float(rc_.y); \
    ACC8(s_, 0, h0_, m_); \
    ACC8(s_, 8, h1_, m_); \
  } \
  uint4 p0_, p1_; \
  p0_.x = f2bf(s_[0])  | ((unsigned)f2bf(s_[1])<<16); \
  p0_.y = f2bf(s_[2])  | ((unsigned)f2bf(s_[3])<<16); \
  p0_.z = f2bf(s_[4])  | ((unsigned)f2bf(s_[5])<<16); \
  p0_.w = f2bf(s_[6])  | ((unsigned)f2bf(s_[7])<<16); \
  p1_.x = f2bf(s_[8])  | ((unsigned)f2bf(s_[9])<<16); \
  p1_.y = f2bf(s_[10]) | ((unsigned)f2bf(s_[11])<<16); \
  p1_.z = f2bf(s_[12]) | ((unsigned)f2bf(s_[13])<<16); \
  p1_.w = f2bf(s_[14]) | ((unsigned)f2bf(s_[15])<<16); \
  char* ab_ = (char*)A_s[(rr)&1] + (row<<8); \
  *(uint4*)(ab_ + (((unsigned)(q*32))    ^ sw)) = p0_; \
  *(uint4*)(ab_ + (((unsigned)(q*32+16)) ^ sw)) = p1_; \
} while(0)

#define MFMA_STEP(rr) do { \
  const char* Ab_ = (const char*)A_s[(rr)&1]; \
  if constexpr (NOUT == 128) { \
    short8 bq_[4]; \
    _Pragma("unroll") \
    for (int ks_=0;ks_<4;++ks_) \
      bq_[ks_] = *(const short8*)(Wt + (((rr)*128 + (w*16 + c16))<<7) + ks_*32 + (g<<3)); \
    _Pragma("unroll") \
    for (int mi_=0;mi_<4;++mi_){ \
      int m_ = mi_*16 + c16; \
      const char* ar_ = Ab_ + (m_<<8); \
      unsigned swr_ = (unsigned)((m_&7)<<4); \
      _Pragma("unroll") \
      for (int ks_=0;ks_<4;++ks_){ \
        short8 a_ = *(const short8*)(ar_ + (((unsigned)((ks_<<6) + (g<<4))) ^ swr_)); \
        acc[mi_] = __builtin_amdgcn_mfma_f32_16x16x32_bf16(a_, bq_[ks_], acc[mi_], 0,0,0); \
      } \
    } \
  } else { \
    const int ni_ = w>>2, ks_ = w&3; \
    short8 bq_ = *(const short8*)(Wt + (((rr)*32 + (ni_*16 + c16))<<7) + ks_*32 + (g<<3)); \
    _Pragma("unroll") \
    for (int mi_=0;mi_<4;++mi_){ \
      int m_ = mi_*16 + c16; \
      const char* ar_ = Ab_ + (m_<<8); \
      unsigned swr_ = (unsigned)((m_&7)<<4); \
      short8 a_ = *(const short8*)(ar_ + (((unsigned)((ks_<<6) + (g<<4))) ^ swr_)); \
      acc[mi_] = __builtin_amdgcn_mfma_f32_16x16x32_bf16(a_, bq_, acc[mi_], 0,0,0); \
    } \
  } \
} while(0)

  // phase 0 (no MFMA)
  LOAD_REC(0, recA, rsA, cntA);
  GATHER(recA, cntA, hgA);
  LOAD_REC(1, recB, rsB, cntB);
  SUMWRITE(0, recA, rsA, cntA, hgA);
  __syncthreads();

  for (int r = 1; r < 15; r += 2) {
    GATHER(recB, cntB, hgB);
    LOAD_REC(r+1, recA, rsA, cntA);
    MFMA_STEP(r-1);
    SUMWRITE(r, recB, rsB, cntB, hgB);
    __syncthreads();
    GATHER(recA, cntA, hgA);
    LOAD_REC(r+2, recB, rsB, cntB);
    MFMA_STEP(r);
    SUMWRITE(r+1, recA, rsA, cntA, hgA);
    __syncthreads();
  }

  // phase 15
  GATHER(recB, cntB, hgB);
  MFMA_STEP(14);
  SUMWRITE(15, recB, rsB, cntB, hgB);
  __syncthreads();
  MFMA_STEP(15);

  if constexpr (NOUT == 128) {
    // stage bf16(relu(acc)) into A_s[0] (swizzled), then vector store
    unsigned short* ob = A_s[0];
    #pragma unroll
    for (int mi=0; mi<4; ++mi)
      #pragma unroll
      for (int j=0; j<4; ++j) {
        int rr = mi*16 + (g<<2) + j;
        int cc = (w<<4) + c16;
        *(unsigned short*)((char*)ob + (rr<<8) +
            (((unsigned)(cc*2)) ^ ((unsigned)((rr&7)<<4)))) =
            f2bf(fmaxf(acc[mi][j], 0.f));
      }
    __syncthreads();
    const char* rb = (const char*)A_s[0] + (row<<8);
    uint4 o0 = *(const uint4*)(rb + (((unsigned)(q*32))    ^ sw));
    uint4 o1 = *(const uint4*)(rb + (((unsigned)(q*32+16)) ^ sw));
    uint4* dp = (uint4*)(h_out + (((size_t)((b<<13) + dst0 + row))<<7) + q*16);
    dp[0] = o0; dp[1] = o1;
  } else {
    // k-split combine: 4 partials per (mi,ni) via LDS atomics
    float* comb = (float*)&A_s[0][0];      // [64][32] fp32 = 8KB
    for (int i = tid; i < TILE*32; i += 512) comb[i] = 0.f;
    __syncthreads();
    const int ni_ = w>>2;
    #pragma unroll
    for (int mi=0; mi<4; ++mi)
      #pragma unroll
      for (int j=0; j<4; ++j) {
        int rr = mi*16 + (g<<2) + j;
        int cc = (ni_<<4) + c16;
        atomicAdd(&comb[rr*32 + cc], acc[mi][j]);
      }
    __syncthreads();
    float4 v = *(const float4*)&comb[row*32 + q*4];
    *(float4*)(logits + ((size_t)((b<<13) + dst0 + row))*32 + q*4) = v;
  }
#undef LOAD_REC
#undef GATHER
#undef ACC8
#undef SUMWRITE
#undef MFMA_STEP
}

__global__ void softmax_k(const float* __restrict__ logits,
                          const float* __restrict__ mobj,
                          float* __restrict__ out){
  int row = blockIdx.x*256 + threadIdx.x;  // 32768 rows
  float v[32];
  const float4* p = (const float4*)(logits + row*32);
  #pragma unroll
  for (int i=0;i<8;i++){
    float4 x = p[i];
    v[4*i]=x.x; v[4*i+1]=x.y; v[4*i+2]=x.z; v[4*i+3]=x.w;
  }
  float mx = v[0];
  #pragma unroll
  for (int i=1;i<32;i++) mx = fmaxf(mx, v[i]);
  float s = 0.f;
  #pragma unroll
  for (int i=0;i<32;i++){ v[i] = __expf(v[i]-mx); s += v[i]; }
  float sc = mobj[row] / s;
  float4* qo = (float4*)(out + row*32);
  #pragma unroll
  for (int i=0;i<8;i++){
    float4 x;
    x.x=v[4*i]*sc; x.y=v[4*i+1]*sc; x.z=v[4*i+2]*sc; x.w=v[4*i+3]*sc;
    qo[i] = x;
  }
}

extern "C" void kernel_launch(void* const* d_in, const int* in_sizes, int n_in,
                              void* d_out, int out_size, void* d_ws, size_t ws_size,
                              hipStream_t stream){
  const int*   cls   = (const int*)  d_in[0];
  // d_in[1] states_objects: unused by reference
  const int*   et    = (const int*)  d_in[2];
  const int*   ec    = (const int*)  d_in[3];
  const float* mobj  = (const float*)d_in[4];
  const float* medge = (const float*)d_in[5];
  const float* emb   = (const float*)d_in[6];
  const float* W1    = (const float*)d_in[7];
  const float* W2    = (const float*)d_in[8];
  const float* W3    = (const float*)d_in[9];
  float* out = (float*)d_out;

  char* ws = (char*)d_ws;
  size_t o = 0;
  auto alloc = [&](size_t bytes)->char*{
    char* p = ws + o;
    o += (bytes + 255) & ~(size_t)255;
    return p;
  };
  unsigned short* hA    = (unsigned short*)alloc((size_t)B_*N_*H_*2);
  unsigned short* hB    = (unsigned short*)alloc((size_t)B_*N_*H_*2);
  float*          lg    = (float*)alloc((size_t)B_*N_*OUT_*4);
  unsigned short* W1t   = (unsigned short*)alloc((size_t)R_*H_*H_*2);
  unsigned short* W2t   = (unsigned short*)alloc((size_t)R_*H_*H_*2);
  unsigned short* W3t   = (unsigned short*)alloc((size_t)R_*OUT_*H_*2);
  int*            cnt   = (int*)alloc((size_t)NKEYS*4);
  int*            off   = (int*)alloc((size_t)(NKEYS+1)*4);
  int*            bsum  = (int*)alloc(512*4);
  uint2*          erec  = (uint2*)alloc((size_t)NEDGE*8);
  (void)ws_size; (void)in_sizes; (void)n_in; (void)out_size;

  // CSR build: histogram -> exclusive scan -> fill (key = (b, rel, dst))
  hipMemsetAsync(cnt, 0, (size_t)NKEYS*4, stream);
  hipLaunchKernelGGL(hist_k,  dim3(NEDGE/256), dim3(256), 0, stream, et, ec, cnt);
  hipLaunchKernelGGL(scan1_k, dim3(512), dim3(256), 0, stream, cnt, off, bsum);
  hipLaunchKernelGGL(scan2_k, dim3(1),   dim3(256), 0, stream, bsum);
  hipLaunchKernelGGL(scan3_k, dim3(512), dim3(256), 0, stream, off, bsum);
  hipMemsetAsync(cnt, 0, (size_t)NKEYS*4, stream);   // cnt -> cursor
  hipLaunchKernelGGL(fill_k,  dim3(NEDGE/256), dim3(256), 0, stream, et, ec, medge, off, cnt, erec);

  // h0 = bf16(embed[class]);  W -> bf16 [r][n][k]
  hipLaunchKernelGGL(embed_k, dim3(B_*N_*32/256), dim3(256), 0, stream, cls, emb, hA);
  hipLaunchKernelGGL(wtrans_all, dim3((2*R_*H_*H_ + R_*OUT_*H_)/256), dim3(256), 0, stream,
                     W1, W2, W3, W1t, W2t, W3t);

  // 3 fused aggregate+GEMM layers, then softmax*mask
  hipLaunchKernelGGL((layer_k<128>), dim3(B_*NTILE), dim3(512), 0, stream,
                     hA, W1t, off, erec, hB, (float*)nullptr);
  hipLaunchKernelGGL((layer_k<128>), dim3(B_*NTILE), dim3(512), 0, stream,
                     hB, W2t, off, erec, hA, (float*)nullptr);
  hipLaunchKernelGGL((layer_k<32>),  dim3(B_*NTILE), dim3(512), 0, stream,
                     hA, W3t, off, erec, (unsigned short*)nullptr, lg);
  hipLaunchKernelGGL(softmax_k, dim3(B_*N_/256), dim3(256), 0, stream, lg, mobj, out);
}

// Round 4
// 300.970 us; speedup vs baseline: 1.4840x; 1.2988x over previous
//
#include <hip/hip_runtime.h>

typedef __attribute__((ext_vector_type(4))) float f32x4;
typedef __attribute__((ext_vector_type(8))) short short8;

#define B_ 4
#define N_ 8192
#define E_ 131072
#define R_ 16
#define H_ 128
#define OUT_ 32
#define NKEYS (B_*N_*R_)   /* 524288 */
#define NEDGE (B_*E_)      /* 524288 */
#define TILE 64
#define NTILE (N_/TILE)    /* 128 */

__device__ __forceinline__ unsigned short f2bf(float f){
  unsigned int u = __float_as_uint(f);
  u = (u + 0x7fffu + ((u>>16)&1u)) >> 16;
  return (unsigned short)u;
}
__device__ __forceinline__ float bfh(unsigned u, int hi){
  return __uint_as_float(hi ? (u & 0xffff0000u) : (u << 16));
}

// ---------------- CSR build: key = ((b*16 + r)*8192 + dst) ----------------

__global__ void hist_k(const int* __restrict__ et, const int* __restrict__ ec,
                       int* __restrict__ cnt){
  int e = blockIdx.x*256 + threadIdx.x;
  int b = e >> 17;                  // E = 2^17
  int dst = et[2*e+1];
  int r  = ec[e];
  atomicAdd(&cnt[(((b<<4)+r)<<13) + dst], 1);
}

__global__ void scan1_k(const int* __restrict__ in, int* __restrict__ out,
                        int* __restrict__ bsum){
  __shared__ int lds[256];
  int t = threadIdx.x;
  int base = blockIdx.x*1024 + t*4;
  int4 v = *(const int4*)(in + base);
  lds[t] = v.x+v.y+v.z+v.w;
  __syncthreads();
  for (int off=1; off<256; off<<=1){
    int x = (t>=off) ? lds[t-off] : 0;
    __syncthreads();
    lds[t] += x;
    __syncthreads();
  }
  if (t==255) bsum[blockIdx.x] = lds[255];
  int pre = (t==0) ? 0 : lds[t-1];
  int4 o;
  o.x = pre; o.y = o.x+v.x; o.z = o.y+v.y; o.w = o.z+v.z;
  *(int4*)(out + base) = o;
}

__global__ void scan2_k(int* __restrict__ bsum){
  __shared__ int lds[256];
  int t = threadIdx.x;
  int2 v = *(const int2*)(bsum + t*2);
  lds[t] = v.x+v.y;
  __syncthreads();
  for (int off=1; off<256; off<<=1){
    int x = (t>=off) ? lds[t-off] : 0;
    __syncthreads();
    lds[t] += x;
    __syncthreads();
  }
  int pre = (t==0) ? 0 : lds[t-1];
  int2 o; o.x = pre; o.y = pre + v.x;
  *(int2*)(bsum + t*2) = o;
}

__global__ void scan3_k(int* __restrict__ out, const int* __restrict__ bsum){
  int t = threadIdx.x;
  int base = blockIdx.x*1024 + t*4;
  int add = bsum[blockIdx.x];
  int4 v = *(int4*)(out + base);
  v.x+=add; v.y+=add; v.z+=add; v.w+=add;
  *(int4*)(out + base) = v;
  if (blockIdx.x==0 && t==0) out[NKEYS] = NEDGE;
}

__global__ void fill_k(const int* __restrict__ et, const int* __restrict__ ec,
                       const float* __restrict__ me, const int* __restrict__ off,
                       int* __restrict__ cur, uint2* __restrict__ erec){
  int e = blockIdx.x*256 + threadIdx.x;
  int b = e >> 17;
  int src = et[2*e];
  int dst = et[2*e+1];
  int r  = ec[e];
  int key = (((b<<4)+r)<<13) + dst;
  int pos = off[key] + atomicAdd(&cur[key], 1);
  erec[pos] = make_uint2((unsigned)src, __float_as_uint(me[e]));
}

// ---------------- feature prep ----------------

__global__ void embed_k(const int* __restrict__ cls, const float* __restrict__ emb,
                        unsigned short* __restrict__ h){
  int t = blockIdx.x*256 + threadIdx.x;   // B*N*32 threads, 4 feats each
  int node = t>>5, c = t&31;
  int cl = cls[node];
  float4 v = *(const float4*)(emb + cl*H_ + c*4);
  uint2 o;
  o.x = f2bf(v.x) | ((unsigned int)f2bf(v.y)<<16);
  o.y = f2bf(v.z) | ((unsigned int)f2bf(v.w)<<16);
  *(uint2*)(h + node*H_ + c*4) = o;
}

// Wt[r][n][k] = bf16(W[r][k][n]); all three W's in one kernel
__global__ void wtrans_all(const float* __restrict__ W1, const float* __restrict__ W2,
                           const float* __restrict__ W3,
                           unsigned short* __restrict__ W1t,
                           unsigned short* __restrict__ W2t,
                           unsigned short* __restrict__ W3t){
  int t = blockIdx.x*256 + threadIdx.x;
  if (t < R_*H_*H_) {
    int k = t & 127, n = (t>>7) & 127, r = t >> 14;
    W1t[t] = f2bf(W1[(r*H_ + k)*H_ + n]);
  } else if (t < 2*R_*H_*H_) {
    int u = t - R_*H_*H_;
    int k = u & 127, n = (u>>7) & 127, r = u >> 14;
    W2t[u] = f2bf(W2[(r*H_ + k)*H_ + n]);
  } else {
    int u = t - 2*R_*H_*H_;
    if (u < R_*OUT_*H_) {
      int k = u & 127, n = (u>>7) & 31, r = u >> 12;
      W3t[u] = f2bf(W3[(r*H_ + k)*OUT_ + n]);
    }
  }
}

// ---------------- fused aggregate + GEMM layer ----------------
// Block = 64 dst rows, 512 threads (8 waves). Thread (row, q) owns a 16-feat
// slice; edge recs prefetched one rel ahead (regs); h gathered into a SINGLE
// hg[4][2] reg buffer (live range does not cross phases -> no spill), issued
// at phase start, consumed after the MFMA step. A-tile bf16 in XOR-swizzled
// LDS, double-buffered -> 1 barrier/rel. blockIdx remapped so each XCD
// serves one batch (h working set 2MB < 4MB L2).

template<int NOUT>
__global__ __launch_bounds__(512, 2) void layer_k(
    const unsigned short* __restrict__ h_in,   // bf16 [B*N*H]
    const unsigned short* __restrict__ Wt,     // bf16 [R][NOUT][H]
    const int* __restrict__ csr_off,
    const uint2* __restrict__ erec,            // {src, mask bits}
    unsigned short* __restrict__ h_out,        // bf16 relu'd (NOUT=128)
    float* __restrict__ logits)                // fp32 (NOUT=32)
{
  __shared__ __align__(16) unsigned short A_s[2][TILE*H_];  // 2 x 16KB
  __shared__ int rowoff_s[R_*(TILE+1)];                     // 4160 B

  const int tid  = threadIdx.x;
  const int lane = tid & 63;
  const int w    = tid >> 6;
  const int c16  = lane & 15;
  const int g    = lane >> 4;
  // XCD-batch affinity: XCD = orig%8 (round-robin dispatch); give each XCD
  // one batch: b = xcd/2, tile = (xcd&1)*64 + orig/8.  Bijective for 512.
  const int orig = blockIdx.x;
  const int xcd  = orig & 7;
  const int b    = xcd >> 1;
  const int dst0 = (((xcd & 1) << 6) + (orig >> 3)) * TILE;
  const int row  = tid >> 3;            // 8 threads per row
  const int q    = tid & 7;             // 16-feat slice
  const unsigned sw = (unsigned)((row & 7) << 4);
  const unsigned short* hb = h_in + ((size_t)b << 20);   // b*N*H

  for (int i = tid; i < R_*(TILE+1); i += 512) {
    int r = i / (TILE+1), rr0 = i - r*(TILE+1);
    rowoff_s[i] = csr_off[(((b<<4)+r)<<13) + dst0 + rr0];
  }
  __syncthreads();

  f32x4 acc[4];
  #pragma unroll
  for (int mi=0; mi<4; ++mi) acc[mi] = f32x4{0.f,0.f,0.f,0.f};

  uint2 recA[4], recB[4];
  uint4 hg[4][2];                      // single gather buffer (no A/B pair)
  int rsA=0, cntA=0, rsB=0, cntB=0;

#define LOAD_REC(rr, rec, rsv, cntv) do { \
  rsv = rowoff_s[(rr)*(TILE+1) + row]; \
  int re_ = rowoff_s[(rr)*(TILE+1) + row + 1]; \
  cntv = re_ - rsv; \
  _Pragma("unroll") \
  for (int i_=0;i_<4;++i_) if (i_ < cntv) rec[i_] = erec[rsv + i_]; \
} while(0)

#define GATHER(rec, cntv) do { \
  _Pragma("unroll") \
  for (int i_=0;i_<4;++i_) if (i_ < cntv) { \
    const uint4* hp_ = (const uint4*)(hb + (((unsigned)rec[i_].x)<<7) + q*16); \
    hg[i_][0] = hp_[0]; hg[i_][1] = hp_[1]; \
  } \
} while(0)

#define ACC8(sarr, base, U4, m_) do { \
  sarr[base+0]+=m_*bfh(U4.x,0); sarr[base+1]+=m_*bfh(U4.x,1); \
  sarr[base+2]+=m_*bfh(U4.y,0); sarr[base+3]+=m_*bfh(U4.y,1); \
  sarr[base+4]+=m_*bfh(U4.z,0); sarr[base+5]+=m_*bfh(U4.z,1); \
  sarr[base+6]+=m_*bfh(U4.w,0); sarr[base+7]+=m_*bfh(U4.w,1); \
} while(0)

#define SUMWRITE(rr, rec, rsv, cntv) do { \
  float s_[16]; \
  _Pragma("unroll") \
  for (int u_=0;u_<16;++u_) s_[u_] = 0.f; \
  _Pragma("unroll") \
  for (int i_=0;i_<4;++i_) if (i_ < cntv) { \
    float m_ = __uint_as_float(rec[i_].y); \
    ACC8(s_, 0, hg[i_][0], m_); \
    ACC8(s_, 8, hg[i_][1], m_); \
  } \
  for (int e_=4; e_<cntv; ++e_) { \
    uint2 rc_ = erec[rsv + e_]; \
    const uint4* hp_ = (const uint4*)(hb + (((unsigned)rc_.x)<<7) + q*16); \
    uint4 h0_ = hp_[0], h1_ = hp_[1]; \
    float m_ = __uint_as_float(rc_.y); \
    ACC8(s_, 0, h0_, m_); \
    ACC8(s_, 8, h1_, m_); \
  } \
  uint4 p0_, p1_; \
  p0_.x = f2bf(s_[0])  | ((unsigned)f2bf(s_[1])<<16); \
  p0_.y = f2bf(s_[2])  | ((unsigned)f2bf(s_[3])<<16); \
  p0_.z = f2bf(s_[4])  | ((unsigned)f2bf(s_[5])<<16); \
  p0_.w = f2bf(s_[6])  | ((unsigned)f2bf(s_[7])<<16); \
  p1_.x = f2bf(s_[8])  | ((unsigned)f2bf(s_[9])<<16); \
  p1_.y = f2bf(s_[10]) | ((unsigned)f2bf(s_[11])<<16); \
  p1_.z = f2bf(s_[12]) | ((unsigned)f2bf(s_[13])<<16); \
  p1_.w = f2bf(s_[14]) | ((unsigned)f2bf(s_[15])<<16); \
  char* ab_ = (char*)A_s[(rr)&1] + (row<<8); \
  *(uint4*)(ab_ + (((unsigned)(q*32))    ^ sw)) = p0_; \
  *(uint4*)(ab_ + (((unsigned)(q*32+16)) ^ sw)) = p1_; \
} while(0)

#define MFMA_STEP(rr) do { \
  const char* Ab_ = (const char*)A_s[(rr)&1]; \
  if constexpr (NOUT == 128) { \
    short8 bq_[4]; \
    _Pragma("unroll") \
    for (int ks_=0;ks_<4;++ks_) \
      bq_[ks_] = *(const short8*)(Wt + (((rr)*128 + (w*16 + c16))<<7) + ks_*32 + (g<<3)); \
    _Pragma("unroll") \
    for (int mi_=0;mi_<4;++mi_){ \
      int m_ = mi_*16 + c16; \
      const char* ar_ = Ab_ + (m_<<8); \
      unsigned swr_ = (unsigned)((m_&7)<<4); \
      _Pragma("unroll") \
      for (int ks_=0;ks_<4;++ks_){ \
        short8 a_ = *(const short8*)(ar_ + (((unsigned)((ks_<<6) + (g<<4))) ^ swr_)); \
        acc[mi_] = __builtin_amdgcn_mfma_f32_16x16x32_bf16(a_, bq_[ks_], acc[mi_], 0,0,0); \
      } \
    } \
  } else { \
    const int ni_ = w>>2, ks_ = w&3; \
    short8 bq_ = *(const short8*)(Wt + (((rr)*32 + (ni_*16 + c16))<<7) + ks_*32 + (g<<3)); \
    _Pragma("unroll") \
    for (int mi_=0;mi_<4;++mi_){ \
      int m_ = mi_*16 + c16; \
      const char* ar_ = Ab_ + (m_<<8); \
      unsigned swr_ = (unsigned)((m_&7)<<4); \
      short8 a_ = *(const short8*)(ar_ + (((unsigned)((ks_<<6) + (g<<4))) ^ swr_)); \
      acc[mi_] = __builtin_amdgcn_mfma_f32_16x16x32_bf16(a_, bq_, acc[mi_], 0,0,0); \
    } \
  } \
} while(0)

  // phase 0 (no MFMA)
  LOAD_REC(0, recA, rsA, cntA);
  GATHER(recA, cntA);
  LOAD_REC(1, recB, rsB, cntB);
  SUMWRITE(0, recA, rsA, cntA);
  __syncthreads();

  for (int r = 1; r < 15; r += 2) {
    GATHER(recB, cntB);
    LOAD_REC(r+1, recA, rsA, cntA);
    MFMA_STEP(r-1);
    SUMWRITE(r, recB, rsB, cntB);
    __syncthreads();
    GATHER(recA, cntA);
    LOAD_REC(r+2, recB, rsB, cntB);
    MFMA_STEP(r);
    SUMWRITE(r+1, recA, rsA, cntA);
    __syncthreads();
  }

  // phase 15
  GATHER(recB, cntB);
  MFMA_STEP(14);
  SUMWRITE(15, recB, rsB, cntB);
  __syncthreads();
  MFMA_STEP(15);

  if constexpr (NOUT == 128) {
    // stage bf16(relu(acc)) into A_s[0] (swizzled), then vector store
    unsigned short* ob = A_s[0];
    #pragma unroll
    for (int mi=0; mi<4; ++mi)
      #pragma unroll
      for (int j=0; j<4; ++j) {
        int rr = mi*16 + (g<<2) + j;
        int cc = (w<<4) + c16;
        *(unsigned short*)((char*)ob + (rr<<8) +
            (((unsigned)(cc*2)) ^ ((unsigned)((rr&7)<<4)))) =
            f2bf(fmaxf(acc[mi][j], 0.f));
      }
    __syncthreads();
    const char* rb = (const char*)A_s[0] + (row<<8);
    uint4 o0 = *(const uint4*)(rb + (((unsigned)(q*32))    ^ sw));
    uint4 o1 = *(const uint4*)(rb + (((unsigned)(q*32+16)) ^ sw));
    uint4* dp = (uint4*)(h_out + (((size_t)((b<<13) + dst0 + row))<<7) + q*16);
    dp[0] = o0; dp[1] = o1;
  } else {
    // k-split combine: 4 partials per (mi,ni) via LDS atomics
    float* comb = (float*)&A_s[0][0];      // [64][32] fp32 = 8KB
    for (int i = tid; i < TILE*32; i += 512) comb[i] = 0.f;
    __syncthreads();
    const int ni_ = w>>2;
    #pragma unroll
    for (int mi=0; mi<4; ++mi)
      #pragma unroll
      for (int j=0; j<4; ++j) {
        int rr = mi*16 + (g<<2) + j;
        int cc = (ni_<<4) + c16;
        atomicAdd(&comb[rr*32 + cc], acc[mi][j]);
      }
    __syncthreads();
    float4 v = *(const float4*)&comb[row*32 + q*4];
    *(float4*)(logits + ((size_t)((b<<13) + dst0 + row))*32 + q*4) = v;
  }
#undef LOAD_REC
#undef GATHER
#undef ACC8
#undef SUMWRITE
#undef MFMA_STEP
}

__global__ void softmax_k(const float* __restrict__ logits,
                          const float* __restrict__ mobj,
                          float* __restrict__ out){
  int row = blockIdx.x*256 + threadIdx.x;  // 32768 rows
  float v[32];
  const float4* p = (const float4*)(logits + row*32);
  #pragma unroll
  for (int i=0;i<8;i++){
    float4 x = p[i];
    v[4*i]=x.x; v[4*i+1]=x.y; v[4*i+2]=x.z; v[4*i+3]=x.w;
  }
  float mx = v[0];
  #pragma unroll
  for (int i=1;i<32;i++) mx = fmaxf(mx, v[i]);
  float s = 0.f;
  #pragma unroll
  for (int i=0;i<32;i++){ v[i] = __expf(v[i]-mx); s += v[i]; }
  float sc = mobj[row] / s;
  float4* qo = (float4*)(out + row*32);
  #pragma unroll
  for (int i=0;i<8;i++){
    float4 x;
    x.x=v[4*i]*sc; x.y=v[4*i+1]*sc; x.z=v[4*i+2]*sc; x.w=v[4*i+3]*sc;
    qo[i] = x;
  }
}

extern "C" void kernel_launch(void* const* d_in, const int* in_sizes, int n_in,
                              void* d_out, int out_size, void* d_ws, size_t ws_size,
                              hipStream_t stream){
  const int*   cls   = (const int*)  d_in[0];
  // d_in[1] states_objects: unused by reference
  const int*   et    = (const int*)  d_in[2];
  const int*   ec    = (const int*)  d_in[3];
  const float* mobj  = (const float*)d_in[4];
  const float* medge = (const float*)d_in[5];
  const float* emb   = (const float*)d_in[6];
  const float* W1    = (const float*)d_in[7];
  const float* W2    = (const float*)d_in[8];
  const float* W3    = (const float*)d_in[9];
  float* out = (float*)d_out;

  char* ws = (char*)d_ws;
  size_t o = 0;
  auto alloc = [&](size_t bytes)->char*{
    char* p = ws + o;
    o += (bytes + 255) & ~(size_t)255;
    return p;
  };
  unsigned short* hA    = (unsigned short*)alloc((size_t)B_*N_*H_*2);
  unsigned short* hB    = (unsigned short*)alloc((size_t)B_*N_*H_*2);
  float*          lg    = (float*)alloc((size_t)B_*N_*OUT_*4);
  unsigned short* W1t   = (unsigned short*)alloc((size_t)R_*H_*H_*2);
  unsigned short* W2t   = (unsigned short*)alloc((size_t)R_*H_*H_*2);
  unsigned short* W3t   = (unsigned short*)alloc((size_t)R_*OUT_*H_*2);
  int*            cnt   = (int*)alloc((size_t)NKEYS*4);
  int*            off   = (int*)alloc((size_t)(NKEYS+1)*4);
  int*            bsum  = (int*)alloc(512*4);
  uint2*          erec  = (uint2*)alloc((size_t)NEDGE*8);
  (void)ws_size; (void)in_sizes; (void)n_in; (void)out_size;

  // CSR build: histogram -> exclusive scan -> fill (key = (b, rel, dst))
  hipMemsetAsync(cnt, 0, (size_t)NKEYS*4, stream);
  hipLaunchKernelGGL(hist_k,  dim3(NEDGE/256), dim3(256), 0, stream, et, ec, cnt);
  hipLaunchKernelGGL(scan1_k, dim3(512), dim3(256), 0, stream, cnt, off, bsum);
  hipLaunchKernelGGL(scan2_k, dim3(1),   dim3(256), 0, stream, bsum);
  hipLaunchKernelGGL(scan3_k, dim3(512), dim3(256), 0, stream, off, bsum);
  hipMemsetAsync(cnt, 0, (size_t)NKEYS*4, stream);   // cnt -> cursor
  hipLaunchKernelGGL(fill_k,  dim3(NEDGE/256), dim3(256), 0, stream, et, ec, medge, off, cnt, erec);

  // h0 = bf16(embed[class]);  W -> bf16 [r][n][k]
  hipLaunchKernelGGL(embed_k, dim3(B_*N_*32/256), dim3(256), 0, stream, cls, emb, hA);
  hipLaunchKernelGGL(wtrans_all, dim3((2*R_*H_*H_ + R_*OUT_*H_)/256), dim3(256), 0, stream,
                     W1, W2, W3, W1t, W2t, W3t);

  // 3 fused aggregate+GEMM layers, then softmax*mask
  hipLaunchKernelGGL((layer_k<128>), dim3(B_*NTILE), dim3(512), 0, stream,
                     hA, W1t, off, erec, hB, (float*)nullptr);
  hipLaunchKernelGGL((layer_k<128>), dim3(B_*NTILE), dim3(512), 0, stream,
                     hB, W2t, off, erec, hA, (float*)nullptr);
  hipLaunchKernelGGL((layer_k<32>),  dim3(B_*NTILE), dim3(512), 0, stream,
                     hA, W3t, off, erec, (unsigned short*)nullptr, lg);
  hipLaunchKernelGGL(softmax_k, dim3(B_*N_/256), dim3(256), 0, stream, lg, mobj, out);
}